// Round 7
// baseline (76.063 us; speedup 1.0000x reference)
//
#include <hip/hip_runtime.h>

#define LN_EPS 1e-5f

typedef float f32x4 __attribute__((ext_vector_type(4)));

static constexpr int Hc    = 512;
static constexpr int Fc    = 16;
static constexpr int Sc    = 1024;
static constexpr int NROWS = 128 * 1024;  // B*S
static constexpr int RPW   = 16;          // rows per wave

// ---- prologue: emb2[s][h] = emb[s][h] + sum_i b[i][h]  (2 MB into d_ws) ----
__global__ void emb2_kernel(const float* __restrict__ b, const float* __restrict__ emb,
                            float* __restrict__ emb2) {
    const int s = blockIdx.x;          // 1024 blocks
    const int h = threadIdx.x * 4;     // 128 threads
    float4 acc = *reinterpret_cast<const float4*>(&emb[s * Hc + h]);
#pragma unroll
    for (int i = 0; i < Fc; ++i) {
        float4 bv = *reinterpret_cast<const float4*>(&b[i * Hc + h]);
        acc.x += bv.x; acc.y += bv.y; acc.z += bv.z; acc.w += bv.w;
    }
    *reinterpret_cast<float4*>(&emb2[s * Hc + h]) = acc;
}

// ---- DPP wave64 sum: 6 VALU steps + readlane, no LDS, no barriers ----
template <int CTRL, int RMASK>
__device__ __forceinline__ float dpp_add(float v) {
    int t = __builtin_amdgcn_update_dpp(0, __float_as_int(v), CTRL, RMASK, 0xf, true);
    return v + __int_as_float(t);
}
__device__ __forceinline__ float wave_sum64(float v) {
    v = dpp_add<0x111, 0xf>(v);   // row_shr:1
    v = dpp_add<0x112, 0xf>(v);   // row_shr:2
    v = dpp_add<0x114, 0xf>(v);   // row_shr:4
    v = dpp_add<0x118, 0xf>(v);   // row_shr:8  -> lane15 of each row16 has row sum
    v = dpp_add<0x142, 0xa>(v);   // row_bcast:15 into rows 1,3
    v = dpp_add<0x143, 0xc>(v);   // row_bcast:31 -> lane63 has total
    return __int_as_float(__builtin_amdgcn_readlane(__float_as_int(v), 63));
}

__device__ __forceinline__ float rdlane(float v, int l) {
    return __int_as_float(__builtin_amdgcn_readlane(__float_as_int(v), l));
}

__device__ __forceinline__ void nt_store4(float* p, float a, float b, float c, float d) {
    f32x4 v; v.x = a; v.y = b; v.z = c; v.w = d;
    __builtin_nontemporal_store(v, reinterpret_cast<f32x4*>(p));
}

// ---- fused: one wave per 16-row group; 8 cols/lane; TWO rows in flight ----
// NOTE: no min-waves in launch_bounds — R4 showed (256,3) caps VGPR at 84 and
// spills the 128-reg W panel (FETCH/WRITE +300 MB each). ~215 regs -> 2 waves/SIMD;
// the 2-row ILP covers the per-row dependency chain instead of more waves.
template <bool FOLDED>
__global__ __launch_bounds__(256) void fused_kernel(
    const float* __restrict__ x, const float* __restrict__ W,
    const float* __restrict__ embp,     // FOLDED ? emb2 : emb
    const float* __restrict__ bsum,     // used only if !FOLDED
    const float* __restrict__ gamma, const float* __restrict__ beta,
    float* __restrict__ out)
{
    const int lane  = threadIdx.x & 63;
    const int wid   = (blockIdx.x << 2) | (threadIdx.x >> 6);
    const int rbase = wid * RPW;
    const int h0 = lane * 4, h1 = h0 + 256;
    const int s0 = rbase & (Sc - 1);    // 16 | rbase, 16 | Sc -> no wrap inside group

    // register-resident W panel: 16 K-rows x 8 cols per lane (128 VGPR)
    float4 w0[Fc], w1[Fc];
#pragma unroll
    for (int i = 0; i < Fc; ++i) {
        w0[i] = *reinterpret_cast<const float4*>(&W[i * Hc + h0]);
        w1[i] = *reinterpret_cast<const float4*>(&W[i * Hc + h1]);
    }

    // x for all 16 rows up front: 4 coalesced dwords/lane
    const float* xb = x + (size_t)rbase * Fc;
    float xq0 = __builtin_nontemporal_load(xb + 0 * 64 + lane);
    float xq1 = __builtin_nontemporal_load(xb + 1 * 64 + lane);
    float xq2 = __builtin_nontemporal_load(xb + 2 * 64 + lane);
    float xq3 = __builtin_nontemporal_load(xb + 3 * 64 + lane);

    const float4 g0  = *reinterpret_cast<const float4*>(&gamma[h0]);
    const float4 g1  = *reinterpret_cast<const float4*>(&gamma[h1]);
    const float4 be0 = *reinterpret_cast<const float4*>(&beta[h0]);
    const float4 be1 = *reinterpret_cast<const float4*>(&beta[h1]);
    float4 bs0, bs1;
    if (!FOLDED) {
        bs0 = *reinterpret_cast<const float4*>(&bsum[h0]);
        bs1 = *reinterpret_cast<const float4*>(&bsum[h1]);
    }

    // current emb pair (rows t, t+1) and next pair (t+2, t+3)
    float4 eC[4], eN[4];
    {
        const float* ea = &embp[(size_t)(s0 + 0) * Hc];
        const float* eb = &embp[(size_t)(s0 + 1) * Hc];
        eC[0] = *reinterpret_cast<const float4*>(&ea[h0]);
        eC[1] = *reinterpret_cast<const float4*>(&ea[h1]);
        eC[2] = *reinterpret_cast<const float4*>(&eb[h0]);
        eC[3] = *reinterpret_cast<const float4*>(&eb[h1]);
    }

#pragma unroll
    for (int tp = 0; tp < RPW / 2; ++tp) {
        const int t = tp * 2;
        // prefetch emb for rows t+2, t+3 (2-3 rows ahead of consumption)
        if (tp < RPW / 2 - 1) {
            const float* ea = &embp[(size_t)(s0 + t + 2) * Hc];
            const float* eb = &embp[(size_t)(s0 + t + 3) * Hc];
            eN[0] = *reinterpret_cast<const float4*>(&ea[h0]);
            eN[1] = *reinterpret_cast<const float4*>(&ea[h1]);
            eN[2] = *reinterpret_cast<const float4*>(&eb[h0]);
            eN[3] = *reinterpret_cast<const float4*>(&eb[h1]);
        }

        const int q = t >> 2;       // pair never straddles an xq (t even)
        const float xsrc = q == 0 ? xq0 : q == 1 ? xq1 : q == 2 ? xq2 : xq3;
        float xsA[Fc], xsB[Fc];
#pragma unroll
        for (int i = 0; i < Fc; ++i) {
            xsA[i] = rdlane(xsrc, ((t    ) & 3) * 16 + i);
            xsB[i] = rdlane(xsrc, ((t + 1) & 3) * 16 + i);
        }

        // two independent FMA trees, interleaved for ILP
        float4 a0A, a1A, a0B, a1B;
        a0A.x = xsA[0]*w0[0].x; a0A.y = xsA[0]*w0[0].y; a0A.z = xsA[0]*w0[0].z; a0A.w = xsA[0]*w0[0].w;
        a1A.x = xsA[0]*w1[0].x; a1A.y = xsA[0]*w1[0].y; a1A.z = xsA[0]*w1[0].z; a1A.w = xsA[0]*w1[0].w;
        a0B.x = xsB[0]*w0[0].x; a0B.y = xsB[0]*w0[0].y; a0B.z = xsB[0]*w0[0].z; a0B.w = xsB[0]*w0[0].w;
        a1B.x = xsB[0]*w1[0].x; a1B.y = xsB[0]*w1[0].y; a1B.z = xsB[0]*w1[0].z; a1B.w = xsB[0]*w1[0].w;
#pragma unroll
        for (int i = 1; i < Fc; ++i) {
            a0A.x = fmaf(xsA[i], w0[i].x, a0A.x);
            a0A.y = fmaf(xsA[i], w0[i].y, a0A.y);
            a0A.z = fmaf(xsA[i], w0[i].z, a0A.z);
            a0A.w = fmaf(xsA[i], w0[i].w, a0A.w);
            a0B.x = fmaf(xsB[i], w0[i].x, a0B.x);
            a0B.y = fmaf(xsB[i], w0[i].y, a0B.y);
            a0B.z = fmaf(xsB[i], w0[i].z, a0B.z);
            a0B.w = fmaf(xsB[i], w0[i].w, a0B.w);
            a1A.x = fmaf(xsA[i], w1[i].x, a1A.x);
            a1A.y = fmaf(xsA[i], w1[i].y, a1A.y);
            a1A.z = fmaf(xsA[i], w1[i].z, a1A.z);
            a1A.w = fmaf(xsA[i], w1[i].w, a1A.w);
            a1B.x = fmaf(xsB[i], w1[i].x, a1B.x);
            a1B.y = fmaf(xsB[i], w1[i].y, a1B.y);
            a1B.z = fmaf(xsB[i], w1[i].z, a1B.z);
            a1B.w = fmaf(xsB[i], w1[i].w, a1B.w);
        }
        a0A.x += eC[0].x; a0A.y += eC[0].y; a0A.z += eC[0].z; a0A.w += eC[0].w;
        a1A.x += eC[1].x; a1A.y += eC[1].y; a1A.z += eC[1].z; a1A.w += eC[1].w;
        a0B.x += eC[2].x; a0B.y += eC[2].y; a0B.z += eC[2].z; a0B.w += eC[2].w;
        a1B.x += eC[3].x; a1B.y += eC[3].y; a1B.z += eC[3].z; a1B.w += eC[3].w;
        if (!FOLDED) {
            a0A.x += bs0.x; a0A.y += bs0.y; a0A.z += bs0.z; a0A.w += bs0.w;
            a1A.x += bs1.x; a1A.y += bs1.y; a1A.z += bs1.z; a1A.w += bs1.w;
            a0B.x += bs0.x; a0B.y += bs0.y; a0B.z += bs0.z; a0B.w += bs0.w;
            a1B.x += bs1.x; a1B.y += bs1.y; a1B.z += bs1.z; a1B.w += bs1.w;
        }

        float psumA = a0A.x + a0A.y + a0A.z + a0A.w + a1A.x + a1A.y + a1A.z + a1A.w;
        float psumB = a0B.x + a0B.y + a0B.z + a0B.w + a1B.x + a1B.y + a1B.z + a1B.w;
        float pssqA = fmaf(a0A.x, a0A.x, fmaf(a0A.y, a0A.y, fmaf(a0A.z, a0A.z, a0A.w * a0A.w)));
        pssqA = fmaf(a1A.x, a1A.x, fmaf(a1A.y, a1A.y, fmaf(a1A.z, a1A.z, fmaf(a1A.w, a1A.w, pssqA))));
        float pssqB = fmaf(a0B.x, a0B.x, fmaf(a0B.y, a0B.y, fmaf(a0B.z, a0B.z, a0B.w * a0B.w)));
        pssqB = fmaf(a1B.x, a1B.x, fmaf(a1B.y, a1B.y, fmaf(a1B.z, a1B.z, fmaf(a1B.w, a1B.w, pssqB))));

        const float sumA = wave_sum64(psumA);
        const float sumB = wave_sum64(psumB);
        const float ssqA = wave_sum64(pssqA);
        const float ssqB = wave_sum64(pssqB);

        const float meanA = sumA * (1.0f / 512.0f);
        const float meanB = sumB * (1.0f / 512.0f);
        const float varA  = ssqA * (1.0f / 512.0f) - meanA * meanA;
        const float varB  = ssqB * (1.0f / 512.0f) - meanB * meanB;
        const float rsA   = rsqrtf(varA + LN_EPS);
        const float rsB   = rsqrtf(varB + LN_EPS);

        float* orowA = out + (size_t)(rbase + t) * Hc;
        float* orowB = out + (size_t)(rbase + t + 1) * Hc;
        nt_store4(&orowA[h0],
                  (a0A.x - meanA) * rsA * g0.x + be0.x,
                  (a0A.y - meanA) * rsA * g0.y + be0.y,
                  (a0A.z - meanA) * rsA * g0.z + be0.z,
                  (a0A.w - meanA) * rsA * g0.w + be0.w);
        nt_store4(&orowA[h1],
                  (a1A.x - meanA) * rsA * g1.x + be1.x,
                  (a1A.y - meanA) * rsA * g1.y + be1.y,
                  (a1A.z - meanA) * rsA * g1.z + be1.z,
                  (a1A.w - meanA) * rsA * g1.w + be1.w);
        nt_store4(&orowB[h0],
                  (a0B.x - meanB) * rsB * g0.x + be0.x,
                  (a0B.y - meanB) * rsB * g0.y + be0.y,
                  (a0B.z - meanB) * rsB * g0.z + be0.z,
                  (a0B.w - meanB) * rsB * g0.w + be0.w);
        nt_store4(&orowB[h1],
                  (a1B.x - meanB) * rsB * g1.x + be1.x,
                  (a1B.y - meanB) * rsB * g1.y + be1.y,
                  (a1B.z - meanB) * rsB * g1.z + be1.z,
                  (a1B.w - meanB) * rsB * g1.w + be1.w);

        // rotate prefetched pair in (renamed away by full unroll)
        eC[0] = eN[0]; eC[1] = eN[1]; eC[2] = eN[2]; eC[3] = eN[3];
    }
}

// bsum fallback prologue (only if ws too small for emb2)
__global__ void bsum_kernel(const float* __restrict__ b, float* __restrict__ bsum) {
    int h = blockIdx.x * 64 + threadIdx.x;
    float s = 0.f;
#pragma unroll
    for (int i = 0; i < Fc; ++i) s += b[i * Hc + h];
    bsum[h] = s;
}

extern "C" void kernel_launch(void* const* d_in, const int* in_sizes, int n_in,
                              void* d_out, int out_size, void* d_ws, size_t ws_size,
                              hipStream_t stream) {
    const float* x     = (const float*)d_in[0];
    const float* W     = (const float*)d_in[1];
    const float* b     = (const float*)d_in[2];
    const float* emb   = (const float*)d_in[3];
    const float* gamma = (const float*)d_in[4];
    const float* beta  = (const float*)d_in[5];
    float* out = (float*)d_out;

    const int blocks = NROWS / (RPW * 4);   // 2048 blocks x 4 waves x 16 rows

    if (ws_size >= (size_t)Sc * Hc * sizeof(float)) {
        float* emb2 = (float*)d_ws;
        emb2_kernel<<<Sc, Hc / 4, 0, stream>>>(b, emb, emb2);
        fused_kernel<true><<<blocks, 256, 0, stream>>>(x, W, emb2, nullptr, gamma, beta, out);
    } else {
        float* bsum = (float*)d_ws;   // 512 floats
        bsum_kernel<<<Hc / 64, 64, 0, stream>>>(b, bsum);
        fused_kernel<false><<<blocks, 256, 0, stream>>>(x, W, emb, bsum, gamma, beta, out);
    }
}

// Round 8
// 74.295 us; speedup vs baseline: 1.0238x; 1.0238x over previous
//
#include <hip/hip_runtime.h>

#define LN_EPS 1e-5f

static constexpr int Hc    = 512;
static constexpr int Fc    = 16;
static constexpr int Sc    = 1024;
static constexpr int NROWS = 128 * 1024;  // B*S
static constexpr int RPW   = 16;          // rows per wave

// ---- prologue: emb2[s][h] = emb[s][h] + sum_i b[i][h]  (2 MB into d_ws) ----
__global__ void emb2_kernel(const float* __restrict__ b, const float* __restrict__ emb,
                            float* __restrict__ emb2) {
    const int s = blockIdx.x;          // 1024 blocks
    const int h = threadIdx.x * 4;     // 128 threads
    float4 acc = *reinterpret_cast<const float4*>(&emb[s * Hc + h]);
#pragma unroll
    for (int i = 0; i < Fc; ++i) {
        float4 bv = *reinterpret_cast<const float4*>(&b[i * Hc + h]);
        acc.x += bv.x; acc.y += bv.y; acc.z += bv.z; acc.w += bv.w;
    }
    *reinterpret_cast<float4*>(&emb2[s * Hc + h]) = acc;
}

// ---- DPP wave64 sum: 6 VALU steps + readlane, no LDS, no barriers ----
template <int CTRL, int RMASK>
__device__ __forceinline__ float dpp_add(float v) {
    int t = __builtin_amdgcn_update_dpp(0, __float_as_int(v), CTRL, RMASK, 0xf, true);
    return v + __int_as_float(t);
}
__device__ __forceinline__ float wave_sum64(float v) {
    v = dpp_add<0x111, 0xf>(v);   // row_shr:1
    v = dpp_add<0x112, 0xf>(v);   // row_shr:2
    v = dpp_add<0x114, 0xf>(v);   // row_shr:4
    v = dpp_add<0x118, 0xf>(v);   // row_shr:8  -> lane15 of each row16 has row sum
    v = dpp_add<0x142, 0xa>(v);   // row_bcast:15 into rows 1,3
    v = dpp_add<0x143, 0xc>(v);   // row_bcast:31 -> lane63 has total
    return __int_as_float(__builtin_amdgcn_readlane(__float_as_int(v), 63));
}

__device__ __forceinline__ float rdlane(float v, int l) {
    return __int_as_float(__builtin_amdgcn_readlane(__float_as_int(v), l));
}

// ---- fused: one wave per 16-row group; 8 cols/lane (h0=lane*4, h1=h0+256) ----
// NOTE: no min-waves in launch_bounds — (256,3) caps VGPR at 84 and spills the
// 128-reg W panel (R4: FETCH/WRITE +300 MB each).
// R8 A/B: PLAIN stores (R6/R7's nontemporal stores both pinned the kernel at
// exactly 268MB/76us = 3.5 TB/s while plain-store memset sustains 7 TB/s).
template <bool FOLDED>
__global__ __launch_bounds__(256) void fused_kernel(
    const float* __restrict__ x, const float* __restrict__ W,
    const float* __restrict__ embp,     // FOLDED ? emb2 : emb
    const float* __restrict__ bsum,     // used only if !FOLDED
    const float* __restrict__ gamma, const float* __restrict__ beta,
    float* __restrict__ out)
{
    const int lane  = threadIdx.x & 63;
    const int wid   = (blockIdx.x << 2) | (threadIdx.x >> 6);
    const int rbase = wid * RPW;
    const int h0 = lane * 4, h1 = h0 + 256;
    const int s0 = rbase & (Sc - 1);    // 16 | rbase, 16 | Sc -> no wrap inside group

    // register-resident W panel: 16 K-rows x 8 cols per lane (128 VGPR)
    float4 w0[Fc], w1[Fc];
#pragma unroll
    for (int i = 0; i < Fc; ++i) {
        w0[i] = *reinterpret_cast<const float4*>(&W[i * Hc + h0]);
        w1[i] = *reinterpret_cast<const float4*>(&W[i * Hc + h1]);
    }

    // x for all 16 rows up front: 4 coalesced dwords/lane (rows rbase+4q..+3)
    const float* xb = x + (size_t)rbase * Fc;
    float xq0 = __builtin_nontemporal_load(xb + 0 * 64 + lane);
    float xq1 = __builtin_nontemporal_load(xb + 1 * 64 + lane);
    float xq2 = __builtin_nontemporal_load(xb + 2 * 64 + lane);
    float xq3 = __builtin_nontemporal_load(xb + 3 * 64 + lane);

    const float4 g0  = *reinterpret_cast<const float4*>(&gamma[h0]);
    const float4 g1  = *reinterpret_cast<const float4*>(&gamma[h1]);
    const float4 be0 = *reinterpret_cast<const float4*>(&beta[h0]);
    const float4 be1 = *reinterpret_cast<const float4*>(&beta[h1]);
    float4 bs0, bs1;
    if (!FOLDED) {
        bs0 = *reinterpret_cast<const float4*>(&bsum[h0]);
        bs1 = *reinterpret_cast<const float4*>(&bsum[h1]);
    }

    // emb ping-pong: even t in eA, odd t in eB; prefetch t=0 now
    float4 eA0 = *reinterpret_cast<const float4*>(&embp[(size_t)s0 * Hc + h0]);
    float4 eA1 = *reinterpret_cast<const float4*>(&embp[(size_t)s0 * Hc + h1]);
    float4 eB0, eB1;

#pragma unroll
    for (int t = 0; t < RPW; ++t) {
        // prefetch e for t+1 into the other slot
        if (t < RPW - 1) {
            const float* en = &embp[(size_t)(s0 + t + 1) * Hc];
            if (t & 1) { eA0 = *reinterpret_cast<const float4*>(&en[h0]);
                         eA1 = *reinterpret_cast<const float4*>(&en[h1]); }
            else       { eB0 = *reinterpret_cast<const float4*>(&en[h0]);
                         eB1 = *reinterpret_cast<const float4*>(&en[h1]); }
        }
        const float4 ec0 = (t & 1) ? eB0 : eA0;
        const float4 ec1 = (t & 1) ? eB1 : eA1;

        const float xsrc = (t >> 2) == 0 ? xq0 : (t >> 2) == 1 ? xq1 : (t >> 2) == 2 ? xq2 : xq3;
        float xs[Fc];
#pragma unroll
        for (int i = 0; i < Fc; ++i)
            xs[i] = rdlane(xsrc, (t & 3) * 16 + i);

        // FMA tree starts from x0*w so the e-load latency hides under it
        float4 a0, a1;
        a0.x = xs[0] * w0[0].x; a0.y = xs[0] * w0[0].y; a0.z = xs[0] * w0[0].z; a0.w = xs[0] * w0[0].w;
        a1.x = xs[0] * w1[0].x; a1.y = xs[0] * w1[0].y; a1.z = xs[0] * w1[0].z; a1.w = xs[0] * w1[0].w;
#pragma unroll
        for (int i = 1; i < Fc; ++i) {
            a0.x = fmaf(xs[i], w0[i].x, a0.x);
            a0.y = fmaf(xs[i], w0[i].y, a0.y);
            a0.z = fmaf(xs[i], w0[i].z, a0.z);
            a0.w = fmaf(xs[i], w0[i].w, a0.w);
            a1.x = fmaf(xs[i], w1[i].x, a1.x);
            a1.y = fmaf(xs[i], w1[i].y, a1.y);
            a1.z = fmaf(xs[i], w1[i].z, a1.z);
            a1.w = fmaf(xs[i], w1[i].w, a1.w);
        }
        a0.x += ec0.x; a0.y += ec0.y; a0.z += ec0.z; a0.w += ec0.w;
        a1.x += ec1.x; a1.y += ec1.y; a1.z += ec1.z; a1.w += ec1.w;
        if (!FOLDED) {
            a0.x += bs0.x; a0.y += bs0.y; a0.z += bs0.z; a0.w += bs0.w;
            a1.x += bs1.x; a1.y += bs1.y; a1.z += bs1.z; a1.w += bs1.w;
        }

        float psum = a0.x + a0.y + a0.z + a0.w + a1.x + a1.y + a1.z + a1.w;
        float pssq = fmaf(a0.x, a0.x, fmaf(a0.y, a0.y, fmaf(a0.z, a0.z, a0.w * a0.w)));
        pssq = fmaf(a1.x, a1.x, fmaf(a1.y, a1.y, fmaf(a1.z, a1.z, fmaf(a1.w, a1.w, pssq))));

        const float sum = wave_sum64(psum);
        const float ssq = wave_sum64(pssq);

        const float mean = sum * (1.0f / 512.0f);
        const float var  = ssq * (1.0f / 512.0f) - mean * mean;
        const float rs   = rsqrtf(var + LN_EPS);

        float4 r0, r1;
        r0.x = (a0.x - mean) * rs * g0.x + be0.x;
        r0.y = (a0.y - mean) * rs * g0.y + be0.y;
        r0.z = (a0.z - mean) * rs * g0.z + be0.z;
        r0.w = (a0.w - mean) * rs * g0.w + be0.w;
        r1.x = (a1.x - mean) * rs * g1.x + be1.x;
        r1.y = (a1.y - mean) * rs * g1.y + be1.y;
        r1.z = (a1.z - mean) * rs * g1.z + be1.z;
        r1.w = (a1.w - mean) * rs * g1.w + be1.w;

        float* orow = out + (size_t)(rbase + t) * Hc;
        *reinterpret_cast<float4*>(&orow[h0]) = r0;   // PLAIN stores (A/B vs NT)
        *reinterpret_cast<float4*>(&orow[h1]) = r1;
    }
}

// bsum fallback prologue (only if ws too small for emb2)
__global__ void bsum_kernel(const float* __restrict__ b, float* __restrict__ bsum) {
    int h = blockIdx.x * 64 + threadIdx.x;
    float s = 0.f;
#pragma unroll
    for (int i = 0; i < Fc; ++i) s += b[i * Hc + h];
    bsum[h] = s;
}

extern "C" void kernel_launch(void* const* d_in, const int* in_sizes, int n_in,
                              void* d_out, int out_size, void* d_ws, size_t ws_size,
                              hipStream_t stream) {
    const float* x     = (const float*)d_in[0];
    const float* W     = (const float*)d_in[1];
    const float* b     = (const float*)d_in[2];
    const float* emb   = (const float*)d_in[3];
    const float* gamma = (const float*)d_in[4];
    const float* beta  = (const float*)d_in[5];
    float* out = (float*)d_out;

    const int blocks = NROWS / (RPW * 4);   // 2048 blocks x 4 waves x 16 rows

    if (ws_size >= (size_t)Sc * Hc * sizeof(float)) {
        float* emb2 = (float*)d_ws;
        emb2_kernel<<<Sc, Hc / 4, 0, stream>>>(b, emb, emb2);
        fused_kernel<true><<<blocks, 256, 0, stream>>>(x, W, emb2, nullptr, gamma, beta, out);
    } else {
        float* bsum = (float*)d_ws;   // 512 floats
        bsum_kernel<<<Hc / 64, 64, 0, stream>>>(b, bsum);
        fused_kernel<false><<<blocks, 256, 0, stream>>>(x, W, emb, bsum, gamma, beta, out);
    }
}

// Round 9
// 70.859 us; speedup vs baseline: 1.0734x; 1.0485x over previous
//
#include <hip/hip_runtime.h>

#define LN_EPS 1e-5f

static constexpr int Hc  = 512;
static constexpr int Fc  = 16;
static constexpr int Sc  = 1024;
static constexpr int Bc  = 128;      // batch
static constexpr int RPW = 16;       // rows per wave: same s, consecutive b

// ---- prologue: bsum[h] = sum_i b[i][h] (512 floats into d_ws) ----
__global__ void bsum_kernel(const float* __restrict__ b, float* __restrict__ bsum) {
    int h = blockIdx.x * 64 + threadIdx.x;
    float s = 0.f;
#pragma unroll
    for (int i = 0; i < Fc; ++i) s += b[i * Hc + h];
    bsum[h] = s;
}

// ---- DPP wave64 sum: 6 VALU steps + readlane, no LDS, no barriers ----
template <int CTRL, int RMASK>
__device__ __forceinline__ float dpp_add(float v) {
    int t = __builtin_amdgcn_update_dpp(0, __float_as_int(v), CTRL, RMASK, 0xf, true);
    return v + __int_as_float(t);
}
__device__ __forceinline__ float wave_sum64(float v) {
    v = dpp_add<0x111, 0xf>(v);   // row_shr:1
    v = dpp_add<0x112, 0xf>(v);   // row_shr:2
    v = dpp_add<0x114, 0xf>(v);   // row_shr:4
    v = dpp_add<0x118, 0xf>(v);   // row_shr:8
    v = dpp_add<0x142, 0xa>(v);   // row_bcast:15
    v = dpp_add<0x143, 0xc>(v);   // row_bcast:31 -> lane63 has total
    return __int_as_float(__builtin_amdgcn_readlane(__float_as_int(v), 63));
}

__device__ __forceinline__ float rdlane(float v, int l) {
    return __int_as_float(__builtin_amdgcn_readlane(__float_as_int(v), l));
}

// ---- fused: one wave per (g, s); rows b*1024+s for b = g*16..g*16+15 ----
// Key point vs R8: emb[s]+bsum is LOOP-INVARIANT (wave fixes s), so the main
// loop has ZERO VMEM loads -> no vmcnt waits coupling to the store queue.
// No min-waves in launch_bounds (R4: (256,3) spilled the W panel).
__global__ __launch_bounds__(256) void fused_kernel(
    const float* __restrict__ x, const float* __restrict__ W,
    const float* __restrict__ emb, const float* __restrict__ bsum,
    const float* __restrict__ gamma, const float* __restrict__ beta,
    float* __restrict__ out)
{
    const int lane = threadIdx.x & 63;
    const int wid  = (blockIdx.x << 2) | (threadIdx.x >> 6);   // 0..8191
    const int s    = wid & (Sc - 1);
    const int g    = wid >> 10;                                // 0..7
    const int h0 = lane * 4, h1 = h0 + 256;

    // register-resident W panel: 16 K-rows x 8 cols per lane (128 VGPR)
    float4 w0[Fc], w1[Fc];
#pragma unroll
    for (int i = 0; i < Fc; ++i) {
        w0[i] = *reinterpret_cast<const float4*>(&W[i * Hc + h0]);
        w1[i] = *reinterpret_cast<const float4*>(&W[i * Hc + h1]);
    }

    // x for all 16 rows up front: 4 gather loads; xq[t4] lane l holds
    // x[row(g*16 + t4*4 + (l>>4), s)][l&15]  (4 x 64B segments per instr)
    const int sub = lane >> 4, i16 = lane & 15;
    float xq0, xq1, xq2, xq3;
    {
        const size_t xoff = (size_t)s * Fc + i16;
        xq0 = __builtin_nontemporal_load(&x[(size_t)(g * 16 + 0 * 4 + sub) * Sc * Fc + xoff]);
        xq1 = __builtin_nontemporal_load(&x[(size_t)(g * 16 + 1 * 4 + sub) * Sc * Fc + xoff]);
        xq2 = __builtin_nontemporal_load(&x[(size_t)(g * 16 + 2 * 4 + sub) * Sc * Fc + xoff]);
        xq3 = __builtin_nontemporal_load(&x[(size_t)(g * 16 + 3 * 4 + sub) * Sc * Fc + xoff]);
    }

    // loop-invariant per-wave vectors
    const float4 g0  = *reinterpret_cast<const float4*>(&gamma[h0]);
    const float4 g1  = *reinterpret_cast<const float4*>(&gamma[h1]);
    const float4 be0 = *reinterpret_cast<const float4*>(&beta[h0]);
    const float4 be1 = *reinterpret_cast<const float4*>(&beta[h1]);
    float4 ebs0, ebs1;
    {
        const float4 e0  = *reinterpret_cast<const float4*>(&emb[(size_t)s * Hc + h0]);
        const float4 e1  = *reinterpret_cast<const float4*>(&emb[(size_t)s * Hc + h1]);
        const float4 bs0 = *reinterpret_cast<const float4*>(&bsum[h0]);
        const float4 bs1 = *reinterpret_cast<const float4*>(&bsum[h1]);
        ebs0.x = e0.x + bs0.x; ebs0.y = e0.y + bs0.y; ebs0.z = e0.z + bs0.z; ebs0.w = e0.w + bs0.w;
        ebs1.x = e1.x + bs1.x; ebs1.y = e1.y + bs1.y; ebs1.z = e1.z + bs1.z; ebs1.w = e1.w + bs1.w;
    }

#pragma unroll
    for (int t = 0; t < RPW; ++t) {
        const float xsrc = (t >> 2) == 0 ? xq0 : (t >> 2) == 1 ? xq1 : (t >> 2) == 2 ? xq2 : xq3;
        float xs[Fc];
#pragma unroll
        for (int i = 0; i < Fc; ++i)
            xs[i] = rdlane(xsrc, (t & 3) * 16 + i);

        // a starts from the loop-invariant ebs (register) -> pure-reg FMA chain
        float4 a0 = ebs0, a1 = ebs1;
#pragma unroll
        for (int i = 0; i < Fc; ++i) {
            a0.x = fmaf(xs[i], w0[i].x, a0.x);
            a0.y = fmaf(xs[i], w0[i].y, a0.y);
            a0.z = fmaf(xs[i], w0[i].z, a0.z);
            a0.w = fmaf(xs[i], w0[i].w, a0.w);
            a1.x = fmaf(xs[i], w1[i].x, a1.x);
            a1.y = fmaf(xs[i], w1[i].y, a1.y);
            a1.z = fmaf(xs[i], w1[i].z, a1.z);
            a1.w = fmaf(xs[i], w1[i].w, a1.w);
        }

        float psum = a0.x + a0.y + a0.z + a0.w + a1.x + a1.y + a1.z + a1.w;
        float pssq = fmaf(a0.x, a0.x, fmaf(a0.y, a0.y, fmaf(a0.z, a0.z, a0.w * a0.w)));
        pssq = fmaf(a1.x, a1.x, fmaf(a1.y, a1.y, fmaf(a1.z, a1.z, fmaf(a1.w, a1.w, pssq))));

        const float sum = wave_sum64(psum);
        const float ssq = wave_sum64(pssq);

        const float mean = sum * (1.0f / 512.0f);
        const float var  = ssq * (1.0f / 512.0f) - mean * mean;
        const float rs   = rsqrtf(var + LN_EPS);

        float4 r0, r1;
        r0.x = (a0.x - mean) * rs * g0.x + be0.x;
        r0.y = (a0.y - mean) * rs * g0.y + be0.y;
        r0.z = (a0.z - mean) * rs * g0.z + be0.z;
        r0.w = (a0.w - mean) * rs * g0.w + be0.w;
        r1.x = (a1.x - mean) * rs * g1.x + be1.x;
        r1.y = (a1.y - mean) * rs * g1.y + be1.y;
        r1.z = (a1.z - mean) * rs * g1.z + be1.z;
        r1.w = (a1.w - mean) * rs * g1.w + be1.w;

        float* orow = out + ((size_t)(g * 16 + t) * Sc + s) * Hc;
        *reinterpret_cast<float4*>(&orow[h0]) = r0;
        *reinterpret_cast<float4*>(&orow[h1]) = r1;
    }
}

extern "C" void kernel_launch(void* const* d_in, const int* in_sizes, int n_in,
                              void* d_out, int out_size, void* d_ws, size_t ws_size,
                              hipStream_t stream) {
    const float* x     = (const float*)d_in[0];
    const float* W     = (const float*)d_in[1];
    const float* b     = (const float*)d_in[2];
    const float* emb   = (const float*)d_in[3];
    const float* gamma = (const float*)d_in[4];
    const float* beta  = (const float*)d_in[5];
    float* out  = (float*)d_out;
    float* bsum = (float*)d_ws;     // 512 floats

    bsum_kernel<<<Hc / 64, 64, 0, stream>>>(b, bsum);

    const int blocks = (8 * Sc) / 4;   // 8192 waves: (g,s) pairs; 4 waves/block
    fused_kernel<<<blocks, 256, 0, stream>>>(x, W, emb, bsum, gamma, beta, out);
}